// Round 2
// baseline (346.725 us; speedup 1.0000x reference)
//
#include <hip/hip_runtime.h>
#include <hip/hip_bf16.h>
#include <math.h>

// GAT layer: B=8, C_in=32, N=2048, L=12, F=32
// out[b,f,w,l] = elu( sum_v Wh[b,l,v,f] * attn[b,v,w] ),
// attn = softmax_v( mask(adj, lrelu(s1[v]+s2[w])) )

#define NEG_INF -9.0e15f

constexpr int Bn  = 8;
constexpr int Cin = 32;
constexpr int Nn  = 2048;
constexpr int Ln  = 12;
constexpr int Fn  = 32;
constexpr int LF  = Ln * Fn;    // 384
constexpr int NW  = Nn / 32;    // 64 bit-words per column

typedef short short8 __attribute__((ext_vector_type(8)));   // 8 x bf16 bits (4 VGPRs)
typedef float f32x4  __attribute__((ext_vector_type(4)));

static __device__ __forceinline__ float lrelu(float x) { return fmaxf(x, 0.2f * x); }

// float -> bf16 bits, round-to-nearest-even (finite inputs only)
static __device__ __forceinline__ unsigned short f2bf(float x) {
    unsigned u = __builtin_bit_cast(unsigned, x);
    u += 0x7FFFu + ((u >> 16) & 1u);
    return (unsigned short)(u >> 16);
}

// ---------------------------------------------------------------------------
// 1. Pack transposed adjacency bitmask: bits[w][vw] bit k = adj[vw*32+k][w] > 0
// ---------------------------------------------------------------------------
__global__ __launch_bounds__(256) void k_adjbits(const int* __restrict__ adj,
                                                 unsigned* __restrict__ bits) {
    int id = blockIdx.x * 256 + threadIdx.x;    // 2048*64 = 131072
    int w  = id & (Nn - 1);
    int vw = id >> 11;                          // 0..63
    unsigned m = 0u;
    int base = vw * 32 * Nn + w;
    #pragma unroll
    for (int k = 0; k < 32; ++k)
        m |= (adj[base + k * Nn] > 0 ? 1u : 0u) << k;
    bits[w * NW + vw] = m;
}

// ---------------------------------------------------------------------------
// 2. Wh projection: WhT[b][l*32+f][v] (bf16 bits), plus s1[b][v], s2[b][v]
// ---------------------------------------------------------------------------
__global__ __launch_bounds__(256) void k_wh(const float* __restrict__ h,
                                            const float* __restrict__ W,
                                            const float* __restrict__ a,
                                            unsigned short* __restrict__ WhT,
                                            float* __restrict__ s1,
                                            float* __restrict__ s2) {
    __shared__ float hs[Cin][8][Ln];   // 12 KB
    __shared__ float Ws[Cin][Fn];      // 4 KB
    int b  = blockIdx.y;
    int n0 = blockIdx.x * 8;
    int tid = threadIdx.x;
    for (int i = tid; i < Cin * Fn; i += 256) Ws[i >> 5][i & 31] = W[i];
    for (int i = tid; i < Cin * 8 * Ln; i += 256) {
        int c = i / (8 * Ln);
        int r = i % (8 * Ln);
        hs[c][r / Ln][r % Ln] = h[(((size_t)b * Cin + c) * Nn + (n0 + r / Ln)) * Ln + (r % Ln)];
    }
    __syncthreads();
    int f  = tid & 31;
    int nl = tid >> 5;
    int n  = n0 + nl;
    float last = 0.f;
    #pragma unroll
    for (int l = 0; l < Ln; ++l) {
        float acc = 0.f;
        #pragma unroll
        for (int c = 0; c < Cin; ++c) acc += hs[c][nl][l] * Ws[c][f];
        WhT[((size_t)b * LF + l * Fn + f) * Nn + n] = f2bf(acc);
        if (l == Ln - 1) last = acc;
    }
    float r1 = last * a[f];
    float r2 = last * a[Fn + f];
    #pragma unroll
    for (int off = 16; off >= 1; off >>= 1) {
        r1 += __shfl_xor(r1, off);
        r2 += __shfl_xor(r2, off);
    }
    if (f == 0) { s1[b * Nn + n] = r1; s2[b * Nn + n] = r2; }
}

// ---------------------------------------------------------------------------
// 3. Column-wise masked max of s1 (partials over i-ranges of 64)
//    monotonicity: max_i lrelu(s1_i + s2_j) = lrelu((max_i s1_i) + s2_j)
// ---------------------------------------------------------------------------
__global__ __launch_bounds__(256) void k_colmax(const unsigned* __restrict__ bits,
                                                const float* __restrict__ s1,
                                                float* __restrict__ cpart) {
    int j  = blockIdx.x * 256 + threadIdx.x;
    int is = blockIdx.y;            // 0..31
    int i0 = is * 64;
    __shared__ float s1s[64][8];    // [i][b]
    int tid = threadIdx.x;
    for (int i = tid; i < 512; i += 256)
        s1s[i & 63][i >> 6] = s1[(i >> 6) * Nn + i0 + (i & 63)];
    __syncthreads();
    float mx[8];
    #pragma unroll
    for (int bb = 0; bb < 8; ++bb) mx[bb] = -1e30f;
    #pragma unroll
    for (int w2 = 0; w2 < 2; ++w2) {
        unsigned bm = bits[j * NW + (i0 >> 5) + w2];
        for (int k = 0; k < 32; ++k) {
            bool on = (bm >> k) & 1u;
            #pragma unroll
            for (int bb = 0; bb < 8; ++bb) {
                float v = s1s[w2 * 32 + k][bb];
                mx[bb] = fmaxf(mx[bb], on ? v : -1e30f);
            }
        }
    }
    #pragma unroll
    for (int bb = 0; bb < 8; ++bb)
        cpart[((size_t)is * 8 + bb) * Nn + j] = mx[bb];
}

// ---------------------------------------------------------------------------
// 4. Finalize column max -> m[b][j]; also E1=exp(s1), E2=exp(0.2 s1)
// ---------------------------------------------------------------------------
__global__ __launch_bounds__(256) void k_mid(const float* __restrict__ cpart,
                                             const float* __restrict__ s1,
                                             const float* __restrict__ s2,
                                             float* __restrict__ m,
                                             float* __restrict__ E1,
                                             float* __restrict__ E2) {
    int id = blockIdx.x * 256 + threadIdx.x;   // 16384 = 8*2048
    float M1 = -1e30f;
    int bb = id >> 11, x = id & (Nn - 1);
    for (int is = 0; is < 32; ++is)
        M1 = fmaxf(M1, cpart[((size_t)is * 8 + bb) * Nn + x]);
    m[id] = fmaxf(lrelu(M1 + s2[id]), NEG_INF);
    float sv = s1[id];
    E1[id] = __expf(sv);
    E2[id] = __expf(0.2f * sv);
}

// ---------------------------------------------------------------------------
// 5. Softmax denominator partials (factorized, no per-element exp):
//    exp(lrelu(s1+s2)-m) = pos ? E1[i]*F1[j] : E2[i]*F2[j]
// ---------------------------------------------------------------------------
__global__ __launch_bounds__(256) void k_denom(const unsigned* __restrict__ bits,
                                               const float* __restrict__ s1,
                                               const float* __restrict__ E1,
                                               const float* __restrict__ E2,
                                               const float* __restrict__ s2,
                                               const float* __restrict__ m,
                                               float* __restrict__ dpart) {
    int j  = blockIdx.x * 256 + threadIdx.x;
    int is = blockIdx.y;
    int i0 = is * 64;
    __shared__ float s1s[64][8], e1s[64][8], e2s[64][8];
    int tid = threadIdx.x;
    for (int i = tid; i < 512; i += 256) {
        int ii = i & 63, bb = i >> 6;
        s1s[ii][bb] = s1[bb * Nn + i0 + ii];
        e1s[ii][bb] = E1[bb * Nn + i0 + ii];
        e2s[ii][bb] = E2[bb * Nn + i0 + ii];
    }
    __syncthreads();
    float F1[8], F2[8], Uv[8], s2v[8], acc[8];
    #pragma unroll
    for (int bb = 0; bb < 8; ++bb) {
        float s2j = s2[bb * Nn + j];
        float mj  = m[bb * Nn + j];
        s2v[bb] = s2j;
        F1[bb]  = __expf(s2j - mj);
        F2[bb]  = __expf(0.2f * s2j - mj);
        Uv[bb]  = (mj == NEG_INF) ? 1.0f : 0.0f;   // all-masked column -> uniform
        acc[bb] = 0.f;
    }
    #pragma unroll
    for (int w2 = 0; w2 < 2; ++w2) {
        unsigned bm = bits[j * NW + (i0 >> 5) + w2];
        for (int k = 0; k < 32; ++k) {
            bool on = (bm >> k) & 1u;
            int i = w2 * 32 + k;
            #pragma unroll
            for (int bb = 0; bb < 8; ++bb) {
                bool pos = (s1s[i][bb] + s2v[bb]) > 0.f;
                float t = (pos ? e1s[i][bb] : e2s[i][bb]) * (pos ? F1[bb] : F2[bb]);
                acc[bb] += on ? t : Uv[bb];
            }
        }
    }
    #pragma unroll
    for (int bb = 0; bb < 8; ++bb)
        dpart[((size_t)is * 8 + bb) * Nn + j] = acc[bb];
}

__global__ __launch_bounds__(256) void k_denomfin(const float* __restrict__ dpart,
                                                  float* __restrict__ rd) {
    int id = blockIdx.x * 256 + threadIdx.x;   // 16384
    int bb = id >> 11, x = id & (Nn - 1);
    float s = 0.f;
    for (int is = 0; is < 32; ++is)
        s += dpart[((size_t)is * 8 + bb) * Nn + x];
    rd[id] = 1.0f / s;
}

// ---------------------------------------------------------------------------
// 6. Fused aggregation GEMM: block = (batch, 32-col tile), full M=384.
//    D[lf, w] = sum_v WhT[lf, v] * P[v, w];  P generated in-register from
//    E1/E2 (LDS) x F1/F2 (per-lane) x adj bitmask.  8 waves, wave = 48 rows
//    (3 row-frags) x 32 cols (2 col-frags), mfma_f32_16x16x32_bf16.
// ---------------------------------------------------------------------------
__global__ __launch_bounds__(512, 4) void k_gemm(const unsigned short* __restrict__ WhT,
                                                 const float* __restrict__ s1,
                                                 const float* __restrict__ s2,
                                                 const float* __restrict__ m_,
                                                 const float* __restrict__ rd,
                                                 const float* __restrict__ E1,
                                                 const float* __restrict__ E2,
                                                 const unsigned* __restrict__ bits,
                                                 float* __restrict__ out) {
    int id = blockIdx.x;            // 512 = 64 wt * 8 b ; id&7==b -> one batch per XCD
    int b_ = id & 7;
    int wt = id >> 3;
    int w0 = wt * 32;
    int tid  = threadIdx.x;
    int lane = tid & 63;
    int wv   = tid >> 6;            // wave 0..7
    int lr   = lane & 15;           // row-in-frag (A) / col-in-frag (B,D)
    int lg   = lane >> 4;           // k-group 0..3
    int rbase = wv * 48;

    __shared__ float s1s[Nn], e1s[Nn], e2s[Nn];   // 24 KB
    for (int i = tid; i < Nn; i += 512) {
        s1s[i] = s1[b_ * Nn + i];
        e1s[i] = E1[b_ * Nn + i];
        e2s[i] = E2[b_ * Nn + i];
    }
    __syncthreads();

    float F1v[2], F2v[2], Uv[2], s2v[2];
    int wcol[2];
    #pragma unroll
    for (int nf = 0; nf < 2; ++nf) {
        int w = w0 + nf * 16 + lr;
        wcol[nf] = w;
        float s2j = s2[b_ * Nn + w];
        float mj  = m_[b_ * Nn + w];
        float rdj = rd[b_ * Nn + w];
        s2v[nf] = s2j;
        F1v[nf] = __expf(s2j - mj) * rdj;
        F2v[nf] = __expf(0.2f * s2j - mj) * rdj;
        Uv[nf]  = (mj == NEG_INF) ? rdj : 0.f;
    }

    f32x4 acc[3][2];
    #pragma unroll
    for (int r = 0; r < 3; ++r)
        #pragma unroll
        for (int nf = 0; nf < 2; ++nf) acc[r][nf] = (f32x4){0.f, 0.f, 0.f, 0.f};

    const unsigned short* Ab = WhT + (size_t)b_ * LF * Nn;

    for (int kv = 0; kv < Nn; kv += 32) {
        int vb = kv + lg * 8;
        short8 af[3];
        #pragma unroll
        for (int r = 0; r < 3; ++r)
            af[r] = *reinterpret_cast<const short8*>(Ab + (size_t)(rbase + r * 16 + lr) * Nn + vb);

        f32x4 sA  = *reinterpret_cast<const f32x4*>(s1s + vb);
        f32x4 sB  = *reinterpret_cast<const f32x4*>(s1s + vb + 4);
        f32x4 eA1 = *reinterpret_cast<const f32x4*>(e1s + vb);
        f32x4 eB1 = *reinterpret_cast<const f32x4*>(e1s + vb + 4);
        f32x4 eA2 = *reinterpret_cast<const f32x4*>(e2s + vb);
        f32x4 eB2 = *reinterpret_cast<const f32x4*>(e2s + vb + 4);
        int widx = kv >> 5;

        #pragma unroll
        for (int nf = 0; nf < 2; ++nf) {
            unsigned bm = bits[wcol[nf] * NW + widx] >> (lg * 8);
            short8 bfv;
            #pragma unroll
            for (int j = 0; j < 8; ++j) {
                float sv = (j < 4) ? sA[j] : sB[j - 4];
                float e1 = (j < 4) ? eA1[j] : eB1[j - 4];
                float e2 = (j < 4) ? eA2[j] : eB2[j - 4];
                bool pos = (sv + s2v[nf]) > 0.f;
                float t = (pos ? e1 : e2) * (pos ? F1v[nf] : F2v[nf]);
                float p = ((bm >> j) & 1u) ? t : Uv[nf];
                bfv[j] = (short)f2bf(p);
            }
            #pragma unroll
            for (int r = 0; r < 3; ++r)
                acc[r][nf] = __builtin_amdgcn_mfma_f32_16x16x32_bf16(af[r], bfv, acc[r][nf], 0, 0, 0);
        }
    }

    // epilogue: D row = rbase + r*16 + lg*4 + q (lf = l*32+f), col = wcol[nf]
    #pragma unroll
    for (int r = 0; r < 3; ++r)
        #pragma unroll
        for (int nf = 0; nf < 2; ++nf)
            #pragma unroll
            for (int q = 0; q < 4; ++q) {
                int lf = rbase + r * 16 + lg * 4 + q;
                int l = lf >> 5, f = lf & 31;
                float v = acc[r][nf][q];
                v = (v > 0.f) ? v : expm1f(v);
                out[(((size_t)b_ * Fn + f) * Nn + wcol[nf]) * Ln + l] = v;
            }
}

// ---------------------------------------------------------------------------
extern "C" void kernel_launch(void* const* d_in, const int* in_sizes, int n_in,
                              void* d_out, int out_size, void* d_ws, size_t ws_size,
                              hipStream_t stream) {
    (void)in_sizes; (void)n_in; (void)out_size; (void)ws_size;
    const float* h   = (const float*)d_in[0];
    const int*   adj = (const int*)d_in[1];
    const float* W   = (const float*)d_in[2];
    const float* a   = (const float*)d_in[3];
    float* out = (float*)d_out;

    char* ws = (char*)d_ws;
    unsigned short* WhT = (unsigned short*)(ws);             // 12,582,912 B
    float*    s1      = (float*)(ws + 12582912);             // 65,536 B each
    float*    s2      = (float*)(ws + 12648448);
    float*    m       = (float*)(ws + 12713984);
    float*    rd      = (float*)(ws + 12779520);
    float*    E1      = (float*)(ws + 12845056);
    float*    E2      = (float*)(ws + 12910592);
    unsigned* bits    = (unsigned*)(ws + 12976128);          // 524,288 B
    float*    cpart   = (float*)(ws + 13500416);             // 2 MB
    float*    dpart   = (float*)(ws + 15597568);             // 2 MB
    // total ~17.7 MB

    k_adjbits<<<512, 256, 0, stream>>>(adj, bits);
    k_wh<<<dim3(256, 8), 256, 0, stream>>>(h, W, a, WhT, s1, s2);
    k_colmax<<<dim3(8, 32), 256, 0, stream>>>(bits, s1, cpart);
    k_mid<<<64, 256, 0, stream>>>(cpart, s1, s2, m, E1, E2);
    k_denom<<<dim3(8, 32), 256, 0, stream>>>(bits, s1, E1, E2, s2, m, dpart);
    k_denomfin<<<64, 256, 0, stream>>>(dpart, rd);
    k_gemm<<<512, 512, 0, stream>>>(WhT, s1, s2, m, rd, E1, E2, bits, out);
}

// Round 3
// 223.905 us; speedup vs baseline: 1.5485x; 1.5485x over previous
//
#include <hip/hip_runtime.h>
#include <hip/hip_bf16.h>
#include <math.h>

// GAT layer: B=8, C_in=32, N=2048, L=12, F=32
// out[b,f,w,l] = elu( sum_v Wh[b,l,v,f] * attn[b,v,w] ),
// attn = softmax_v( mask(adj, lrelu(s1[v]+s2[w])) )
//
// Softmax shift uses per-batch global max Mb (valid; all exp args <= 0).
// Factorized exp: t = pos ? E1[v]*F1[w] : E2[v]*F2[w],
//   E1=exp(s1), E2=exp(0.2 s1), F1=exp(s2-m), F2=exp(0.2 s2-m), m=lrelu(Mb+s2).
// pos test: s1+s2>0  <=>  E1[v] > exp(-s2[w])  (monotone exp).
// Denominator accumulated inside the GEMM; normalize in epilogue.

constexpr int Cin = 32;
constexpr int Nn  = 2048;
constexpr int Ln  = 12;
constexpr int Fn  = 32;
constexpr int LF  = Ln * Fn;    // 384
constexpr int NW  = Nn / 32;    // 64 bit-words per column
constexpr int CH  = 128;        // K-chunk (v per LDS stage)
constexpr int NCH = Nn / CH;    // 16
constexpr int WT  = 64;         // w columns per block
constexpr int MH  = 192;        // rows per block (M split in 2)

typedef short short8 __attribute__((ext_vector_type(8)));   // 8 x bf16 bits
typedef float f32x4  __attribute__((ext_vector_type(4)));

// float -> bf16 bits, round-to-nearest-even (finite inputs only)
static __device__ __forceinline__ unsigned short f2bf(float x) {
    unsigned u = __builtin_bit_cast(unsigned, x);
    u += 0x7FFFu + ((u >> 16) & 1u);
    return (unsigned short)(u >> 16);
}

// ---------------------------------------------------------------------------
// 1. Pack transposed adjacency bitmask: bits[w][vw] bit k = adj[vw*32+k][w] > 0
// ---------------------------------------------------------------------------
__global__ __launch_bounds__(256) void k_adjbits(const int* __restrict__ adj,
                                                 unsigned* __restrict__ bits) {
    int id = blockIdx.x * 256 + threadIdx.x;    // 131072
    int w  = id & (Nn - 1);
    int vw = id >> 11;                          // 0..63
    unsigned m = 0u;
    int base = vw * 32 * Nn + w;
    #pragma unroll
    for (int k = 0; k < 32; ++k)
        m |= (adj[base + k * Nn] > 0 ? 1u : 0u) << k;
    bits[w * NW + vw] = m;
}

// ---------------------------------------------------------------------------
// 2. Wh projection: WhT[b][l*32+f][v] (bf16 bits) + s1, s2, E1, E2
// ---------------------------------------------------------------------------
__global__ __launch_bounds__(256) void k_wh(const float* __restrict__ h,
                                            const float* __restrict__ W,
                                            const float* __restrict__ a,
                                            unsigned short* __restrict__ WhT,
                                            float* __restrict__ s1,
                                            float* __restrict__ s2,
                                            float* __restrict__ E1,
                                            float* __restrict__ E2) {
    __shared__ float hs[Cin][8][Ln];   // 12 KB
    __shared__ float Ws[Cin][Fn];      // 4 KB
    int b  = blockIdx.y;
    int n0 = blockIdx.x * 8;
    int tid = threadIdx.x;
    for (int i = tid; i < Cin * Fn; i += 256) Ws[i >> 5][i & 31] = W[i];
    for (int i = tid; i < Cin * 8 * Ln; i += 256) {
        int c = i / (8 * Ln);
        int r = i % (8 * Ln);
        hs[c][r / Ln][r % Ln] = h[(((size_t)b * Cin + c) * Nn + (n0 + r / Ln)) * Ln + (r % Ln)];
    }
    __syncthreads();
    int f  = tid & 31;
    int nl = tid >> 5;
    int n  = n0 + nl;
    float last = 0.f;
    #pragma unroll
    for (int l = 0; l < Ln; ++l) {
        float acc = 0.f;
        #pragma unroll
        for (int c = 0; c < Cin; ++c) acc += hs[c][nl][l] * Ws[c][f];
        WhT[((size_t)b * LF + l * Fn + f) * Nn + n] = f2bf(acc);
        if (l == Ln - 1) last = acc;
    }
    float r1 = last * a[f];
    float r2 = last * a[Fn + f];
    #pragma unroll
    for (int off = 16; off >= 1; off >>= 1) {
        r1 += __shfl_xor(r1, off);
        r2 += __shfl_xor(r2, off);
    }
    if (f == 0) {
        s1[b * Nn + n] = r1;
        s2[b * Nn + n] = r2;
        E1[b * Nn + n] = __expf(r1);
        E2[b * Nn + n] = __expf(0.2f * r1);
    }
}

// ---------------------------------------------------------------------------
// 3. Per-batch global max of s1
// ---------------------------------------------------------------------------
__global__ __launch_bounds__(256) void k_smax(const float* __restrict__ s1,
                                              float* __restrict__ Mb) {
    int b = blockIdx.x;
    float m = -1e30f;
    for (int i = threadIdx.x; i < Nn; i += 256) m = fmaxf(m, s1[b * Nn + i]);
    #pragma unroll
    for (int off = 32; off >= 1; off >>= 1) m = fmaxf(m, __shfl_xor(m, off));
    __shared__ float wr[4];
    if ((threadIdx.x & 63) == 0) wr[threadIdx.x >> 6] = m;
    __syncthreads();
    if (threadIdx.x == 0)
        Mb[b] = fmaxf(fmaxf(wr[0], wr[1]), fmaxf(wr[2], wr[3]));
}

// ---------------------------------------------------------------------------
// 4. Per-column empty flag (b-independent): empty[w] = (no bits set in column)
// ---------------------------------------------------------------------------
__global__ __launch_bounds__(256) void k_colinfo(const unsigned* __restrict__ bits,
                                                 int* __restrict__ empty) {
    int w = blockIdx.x * 256 + threadIdx.x;    // grid 8 -> 2048
    const uint4* p = (const uint4*)(bits + (size_t)w * NW);
    unsigned acc = 0;
    #pragma unroll
    for (int i = 0; i < 16; ++i) { uint4 v = p[i]; acc |= v.x | v.y | v.z | v.w; }
    empty[w] = (acc == 0u) ? 1 : 0;
}

// ---------------------------------------------------------------------------
// 5. Fused aggregation GEMM with cooperative P staging + in-kernel denominator.
//    Block: 256 thr (4 waves), covers MH=192 rows x WT=64 cols of one batch.
//    Per chunk (128 v): all threads gen P[64][128] bf16 into swizzled LDS
//    (double-buffered), accumulate column sums; waves run 48 MFMA each.
// ---------------------------------------------------------------------------
__global__ __launch_bounds__(256, 2) void k_gemm(const unsigned short* __restrict__ WhT,
                                                 const float* __restrict__ s2,
                                                 const float* __restrict__ Mb,
                                                 const float* __restrict__ E1,
                                                 const float* __restrict__ E2,
                                                 const unsigned* __restrict__ bits,
                                                 const int* __restrict__ empty,
                                                 float* __restrict__ out) {
    int id = blockIdx.x;            // 512; id&7==b -> one batch per XCD
    int b_ = id & 7;
    int r2 = id >> 3;               // 0..63
    int wt = r2 & 31;               // w-tile
    int mh = r2 >> 5;               // m-half
    int w0 = wt * WT;
    int tid  = threadIdx.x;
    int lane = tid & 63;
    int wv   = tid >> 6;            // wave 0..3
    int lr   = lane & 15;
    int lg   = lane >> 4;
    int rbase = mh * MH + wv * 48;

    __shared__ unsigned short P[2][WT * CH];   // 2 x 16 KB, XOR-swizzled
    __shared__ float denom[WT];

    // P-gen mapping: thread = 8 v (vgrp) x 4 w (wgrp)
    int vgrp = tid & 15;
    int wgrp = tid >> 4;
    int vs   = vgrp * 8;

    const float* E1b = E1 + (size_t)b_ * Nn;
    const float* E2b = E2 + (size_t)b_ * Nn;

    float F1[4], F2[4], G[4], Uv[4];
    float MbV = Mb[b_];
    #pragma unroll
    for (int i = 0; i < 4; ++i) {
        int w = w0 + wgrp * 4 + i;
        float s2w = s2[(size_t)b_ * Nn + w];
        float mz  = MbV + s2w;
        float mw  = fmaxf(mz, 0.2f * mz);              // lrelu
        F1[i] = __expf(s2w - mw);
        F2[i] = __expf(0.2f * s2w - mw);
        G[i]  = __expf(-s2w);
        Uv[i] = empty[w] ? 1.0f : 0.0f;
    }

    if (tid < WT) denom[tid] = 0.f;
    __syncthreads();

    auto gen = [&](int c, int buf) {
        int v0 = c * CH + vs;
        f32x4 e1a = *(const f32x4*)(E1b + v0);
        f32x4 e1b = *(const f32x4*)(E1b + v0 + 4);
        f32x4 e2a = *(const f32x4*)(E2b + v0);
        f32x4 e2b = *(const f32x4*)(E2b + v0 + 4);
        int wi = v0 >> 5;
        int sh = v0 & 31;
        float dsum[4];
        #pragma unroll
        for (int i = 0; i < 4; ++i) {
            int wl = wgrp * 4 + i;
            unsigned bm = (bits[(size_t)(w0 + wl) * NW + wi] >> sh) & 0xffu;
            short8 sv;
            float ds = 0.f;
            #pragma unroll
            for (int j = 0; j < 8; ++j) {
                float e1 = (j < 4) ? e1a[j] : e1b[j - 4];
                float e2 = (j < 4) ? e2a[j] : e2b[j - 4];
                bool pos = e1 > G[i];
                float t = (pos ? e1 : e2) * (pos ? F1[i] : F2[i]);
                float p = ((bm >> j) & 1u) ? t : Uv[i];
                ds += p;
                sv[j] = (short)f2bf(p);
            }
            int idx = (wl * CH + vs) ^ ((wl & 7) << 3);
            *(short8*)&P[buf][idx] = sv;
            dsum[i] = ds;
        }
        // reduce over the 16 v-lanes (same wgrp), then single-writer RMW
        #pragma unroll
        for (int off = 1; off < 16; off <<= 1) {
            #pragma unroll
            for (int i = 0; i < 4; ++i) dsum[i] += __shfl_xor(dsum[i], off);
        }
        if (vgrp == 0) {
            #pragma unroll
            for (int i = 0; i < 4; ++i) denom[wgrp * 4 + i] += dsum[i];
        }
    };

    f32x4 acc[3][4];
    #pragma unroll
    for (int r = 0; r < 3; ++r)
        #pragma unroll
        for (int nf = 0; nf < 4; ++nf) acc[r][nf] = (f32x4){0.f, 0.f, 0.f, 0.f};

    const unsigned short* Ab = WhT + (size_t)b_ * LF * Nn;
    const unsigned short* Arow[3];
    #pragma unroll
    for (int r = 0; r < 3; ++r)
        Arow[r] = Ab + (size_t)(rbase + r * 16 + lr) * Nn;

    auto mfma_chunk = [&](int c, int buf) {
        #pragma unroll
        for (int ks = 0; ks < 4; ++ks) {
            int vb = c * CH + ks * 32 + lg * 8;
            short8 af[3];
            #pragma unroll
            for (int r = 0; r < 3; ++r)
                af[r] = *(const short8*)(Arow[r] + vb);
            #pragma unroll
            for (int nf = 0; nf < 4; ++nf) {
                int row = nf * 16 + lr;
                int idx = (row * CH + ks * 32 + lg * 8) ^ ((row & 7) << 3);
                short8 bf = *(const short8*)&P[buf][idx];
                #pragma unroll
                for (int r = 0; r < 3; ++r)
                    acc[r][nf] = __builtin_amdgcn_mfma_f32_16x16x32_bf16(af[r], bf, acc[r][nf], 0, 0, 0);
            }
        }
    };

    gen(0, 0);
    __syncthreads();
    for (int c = 0; c < NCH - 1; ++c) {
        gen(c + 1, (c + 1) & 1);    // writes other buffer (global loads issue early)
        mfma_chunk(c, c & 1);       // reads current buffer
        __syncthreads();
    }
    mfma_chunk(NCH - 1, (NCH - 1) & 1);
    // denom complete since before last barrier

    float rdv[4];
    #pragma unroll
    for (int nf = 0; nf < 4; ++nf) rdv[nf] = 1.0f / denom[nf * 16 + lr];

    #pragma unroll
    for (int r = 0; r < 3; ++r)
        #pragma unroll
        for (int nf = 0; nf < 4; ++nf)
            #pragma unroll
            for (int q = 0; q < 4; ++q) {
                int lf = rbase + r * 16 + lg * 4 + q;
                int l = lf >> 5, f = lf & 31;
                float v = acc[r][nf][q] * rdv[nf];
                v = (v > 0.f) ? v : expm1f(v);
                out[(((size_t)b_ * Fn + f) * Nn + (w0 + nf * 16 + lr)) * Ln + l] = v;
            }
}

// ---------------------------------------------------------------------------
extern "C" void kernel_launch(void* const* d_in, const int* in_sizes, int n_in,
                              void* d_out, int out_size, void* d_ws, size_t ws_size,
                              hipStream_t stream) {
    (void)in_sizes; (void)n_in; (void)out_size; (void)ws_size;
    const float* h   = (const float*)d_in[0];
    const int*   adj = (const int*)d_in[1];
    const float* W   = (const float*)d_in[2];
    const float* a   = (const float*)d_in[3];
    float* out = (float*)d_out;

    char* ws = (char*)d_ws;
    unsigned short* WhT = (unsigned short*)(ws);             // 12,582,912 B
    float*    s1    = (float*)(ws + 12582912);               // 64 KB each
    float*    s2    = (float*)(ws + 12648448);
    float*    E1    = (float*)(ws + 12713984);
    float*    E2    = (float*)(ws + 12779520);
    float*    Mb    = (float*)(ws + 12845056);               // 32 B (pad 256)
    unsigned* bits  = (unsigned*)(ws + 12845312);            // 512 KB
    int*      empty = (int*)(ws + 13369600);                 // 8 KB
    // total ~13.4 MB

    k_adjbits<<<512, 256, 0, stream>>>(adj, bits);
    k_wh<<<dim3(256, 8), 256, 0, stream>>>(h, W, a, WhT, s1, s2, E1, E2);
    k_smax<<<8, 256, 0, stream>>>(s1, Mb);
    k_colinfo<<<8, 256, 0, stream>>>(bits, empty);
    k_gemm<<<512, 256, 0, stream>>>(WhT, s2, Mb, E1, E2, bits, empty, out);
}